// Round 9
// baseline (492.445 us; speedup 1.0000x reference)
//
#include <hip/hip_runtime.h>

#define CCH 512
#define HW  4096

typedef __attribute__((ext_vector_type(8))) short short8;
typedef __attribute__((ext_vector_type(8))) _Float16 half8;
typedef __attribute__((ext_vector_type(4))) float f4;

__device__ __forceinline__ unsigned short f2bf(float x){
  unsigned u = __builtin_bit_cast(unsigned, x);
  u += 0x7FFFu + ((u >> 16) & 1u);
  return (unsigned short)(u >> 16);
}
__device__ __forceinline__ float bf2f(unsigned short h){
  unsigned u = ((unsigned)h) << 16;
  return __builtin_bit_cast(float, u);
}
__device__ __forceinline__ unsigned short f2h(float x){
  _Float16 h = (_Float16)x;
  return __builtin_bit_cast(unsigned short, h);
}
__device__ __forceinline__ f4 ld_bf4(const unsigned short* p){
  ushort4 u = *(const ushort4*)p;
  f4 r; r[0]=bf2f(u.x); r[1]=bf2f(u.y); r[2]=bf2f(u.z); r[3]=bf2f(u.w);
  return r;
}
__device__ __forceinline__ f4 shfl_xor4(f4 v, int mask){
  f4 r;
  #pragma unroll
  for(int k = 0; k < 4; ++k) r[k] = __shfl_xor(v[k], mask);
  return r;
}

// ---- K0a/K0b: weight dtype conversion ----
__global__ void wsplit_bf_kernel(const float* __restrict__ src,
                                 unsigned short* __restrict__ dst, int n){
  int i = blockIdx.x * 256 + threadIdx.x;
  if(i < n) dst[i] = f2bf(src[i]);
}
__global__ void wsplit_h_kernel(const float* __restrict__ src,
                                unsigned short* __restrict__ dst, int n){
  int i = blockIdx.x * 256 + threadIdx.x;
  if(i < n) dst[i] = f2h(src[i]);
}

// ---- K2: fused LN stats + apply + transpose -> bf16 xt[p][c]. Block = 32 px x 512 c. ----
__global__ __launch_bounds__(256)
void ln_tr_fused(const float* __restrict__ x, const float* __restrict__ g,
                 unsigned short* __restrict__ xt){
  __shared__ unsigned short xs[512][32];
  __shared__ float gln[512];
  __shared__ f4 red_s[4][8], red_ss[4][8];
  __shared__ float sm[32], sr[32];
  int pix0 = blockIdx.x * 32;
  int bl = pix0 >> 12, p0 = pix0 & 4095;
  int t = threadIdx.x, lane = t & 63, wid = t >> 6;
  gln[t] = g[t]; gln[t + 256] = g[t + 256];
  int j = t & 7;
  f4 s4 = {0,0,0,0}, ss4 = {0,0,0,0};
  for(int ci = t >> 3; ci < 512; ci += 32){
    f4 v = *(const f4*)(x + ((size_t)(bl*512 + ci)) * HW + p0 + j*4);
    s4 += v; ss4 += v * v;
    ushort4 b;
    b.x = f2bf(v[0]); b.y = f2bf(v[1]); b.z = f2bf(v[2]); b.w = f2bf(v[3]);
    *(ushort4*)&xs[ci][j*4] = b;
  }
  #pragma unroll
  for(int m = 8; m < 64; m <<= 1){ s4 += shfl_xor4(s4, m); ss4 += shfl_xor4(ss4, m); }
  if((lane >> 3) == 0){ red_s[wid][j] = s4; red_ss[wid][j] = ss4; }
  __syncthreads();
  if(t < 32){
    int jj = t >> 2, k = t & 3;
    const float* rs = (const float*)red_s;
    const float* rss = (const float*)red_ss;
    float s = 0.f, ss = 0.f;
    #pragma unroll
    for(int w = 0; w < 4; ++w){ s += rs[(w*8 + jj)*4 + k]; ss += rss[(w*8 + jj)*4 + k]; }
    float m = s * (1.0f/512.0f);
    float var = ss * (1.0f/512.0f) - m*m;
    sm[t] = m; sr[t] = rsqrtf(var + 1e-5f);
  }
  __syncthreads();
  int px = t & 31, cs = t >> 5;
  float m = sm[px], r = sr[px];
  for(int i = 0; i < 8; ++i){
    int c0 = cs * 64 + i * 8;
    short8 o;
    #pragma unroll
    for(int k = 0; k < 8; ++k){
      float f = bf2f(xs[c0 + k][px]);
      o[k] = (short)f2bf((f - m) * r * gln[c0 + k]);
    }
    *(short8*)(xt + ((size_t)(pix0 + px)) * 512 + c0) = o;
  }
}

// ---- K3: QKV GEMM. B staged via gload_lds (XOR swizzle); A streamed DIRECTLY from
// global/L2 into registers (A = 1.5MB, L2-resident). LDS 16KB -> up to 8 blocks/CU
// resident: barrier drains hidden by TLP (the lever every prior retile lost).
__global__ __launch_bounds__(256, 2)
void gemm_bt_kernel(const unsigned short* __restrict__ A,
                    const unsigned short* __restrict__ B,
                    unsigned short* __restrict__ Out, size_t bufStride){
  __shared__ unsigned short sB[128][64];
  int bl = blockIdx.z;
  const unsigned short* bsrc = B + (size_t)bl * HW * CCH;
  int p0 = blockIdx.x * 128;
  int oA = blockIdx.y * 128;
  int o0 = (blockIdx.y & 3) * 128;
  int buf = blockIdx.y >> 2;
  int t = threadIdx.x, lane = t & 63, wid = t >> 6;
  int wr = wid >> 1, wc = wid & 1;
  int kl = lane & 15, kh = lane >> 4;
  int srow  = lane >> 3;
  int scol8 = ((lane & 7) ^ srow) * 8;
  // per-lane A row bases (4 mi rows), fragment column kh*8
  const unsigned short* aB[4];
  #pragma unroll
  for(int mi = 0; mi < 4; ++mi)
    aB[mi] = A + (size_t)(oA + wr*64 + mi*16 + kl) * CCH + kh*8;
  f4 acc[4][4] = {};
  for(int k0 = 0; k0 < CCH; k0 += 64){
    #pragma unroll
    for(int i = 0; i < 4; ++i){
      int r = wid * 32 + i * 8;
      const unsigned short* gB = bsrc + (size_t)(p0 + r + srow) * CCH + k0 + scol8;
      __builtin_amdgcn_global_load_lds(
          (const __attribute__((address_space(1))) void*)gB,
          (__attribute__((address_space(3))) void*)&sB[r][0], 16, 0, 0);
    }
    __syncthreads();
    #pragma unroll
    for(int kk = 0; kk < 64; kk += 32){
      int ka = kk + kh * 8;
      short8 af[4], bf[4];
      #pragma unroll
      for(int mi = 0; mi < 4; ++mi)
        af[mi] = *(const short8*)(aB[mi] + k0 + kk);
      #pragma unroll
      for(int ni = 0; ni < 4; ++ni){
        int row = wc*64 + ni*16 + kl;
        bf[ni] = *(const short8*)&sB[row][(((ka >> 3) ^ (row & 7)) * 8)];
      }
      #pragma unroll
      for(int mi = 0; mi < 4; ++mi)
        #pragma unroll
        for(int ni = 0; ni < 4; ++ni)
          acc[mi][ni] = __builtin_amdgcn_mfma_f32_16x16x32_bf16(af[mi], bf[ni], acc[mi][ni], 0, 0, 0);
    }
    __syncthreads();
  }
  unsigned short* op = Out + (size_t)buf * bufStride + (size_t)bl * CCH * HW;
  #pragma unroll
  for(int mi = 0; mi < 4; ++mi){
    int oq = (o0 + wr*64 + mi*16) / 4 + kh;
    #pragma unroll
    for(int ni = 0; ni < 4; ++ni){
      int p = p0 + wc*64 + ni*16 + kl;
      uint2 pk;
      pk.x = (unsigned)f2bf(acc[mi][ni][0]) | ((unsigned)f2bf(acc[mi][ni][1]) << 16);
      pk.y = (unsigned)f2bf(acc[mi][ni][2]) | ((unsigned)f2bf(acc[mi][ni][3]) << 16);
      *(uint2*)(op + ((size_t)oq * HW + p) * 4) = pk;
    }
  }
}

// ---- K6: fused out-GEMM + final LN. Tile 512(ch) x 64(px), 256 thr, 2 blocks/CU. ----
__global__ __launch_bounds__(256, 2)
void outln_kernel(const unsigned short* __restrict__ W, const unsigned short* __restrict__ att,
                  const float* __restrict__ g, float* __restrict__ outp){
  __shared__ unsigned short sA[512][64], sB[64][64];
  __shared__ float ps[4][64], pss[4][64];
  __shared__ float gsh[512];
  int bl = blockIdx.y;
  int p0 = blockIdx.x * 64;
  const unsigned short* bsrc = att + (size_t)bl * HW * CCH;
  int t = threadIdx.x, lane = t & 63, wid = t >> 6;
  int kl = lane & 15, kh = lane >> 4;
  int srow  = lane >> 3;
  int scol8 = ((lane & 7) ^ srow) * 8;
  gsh[t] = g[t]; gsh[t + 256] = g[t + 256];
  f4 acc[8][4] = {};
  for(int kt = 0; kt < 8; ++kt){
    int k0 = kt * 64;
    #pragma unroll
    for(int i = 0; i < 16; ++i){
      int r = wid * 128 + i * 8;
      const unsigned short* gA = W + (size_t)(r + srow) * CCH + k0 + scol8;
      __builtin_amdgcn_global_load_lds(
          (const __attribute__((address_space(1))) void*)gA,
          (__attribute__((address_space(3))) void*)&sA[r][0], 16, 0, 0);
    }
    #pragma unroll
    for(int i = 0; i < 2; ++i){
      int r = wid * 16 + i * 8;
      const unsigned short* gB = bsrc + (size_t)(p0 + r + srow) * CCH + k0 + scol8;
      __builtin_amdgcn_global_load_lds(
          (const __attribute__((address_space(1))) void*)gB,
          (__attribute__((address_space(3))) void*)&sB[r][0], 16, 0, 0);
    }
    __syncthreads();
    #pragma unroll
    for(int kk = 0; kk < 64; kk += 32){
      int ka = kk + kh * 8;
      short8 af[8], bf[4];
      #pragma unroll
      for(int mi = 0; mi < 8; ++mi){
        int row = wid*128 + mi*16 + kl;
        af[mi] = *(const short8*)&sA[row][(((ka >> 3) ^ (row & 7)) * 8)];
      }
      #pragma unroll
      for(int ni = 0; ni < 4; ++ni){
        int row = ni*16 + kl;
        bf[ni] = *(const short8*)&sB[row][(((ka >> 3) ^ (row & 7)) * 8)];
      }
      #pragma unroll
      for(int mi = 0; mi < 8; ++mi)
        #pragma unroll
        for(int ni = 0; ni < 4; ++ni)
          acc[mi][ni] = __builtin_amdgcn_mfma_f32_16x16x32_f16(
              __builtin_bit_cast(half8, af[mi]), __builtin_bit_cast(half8, bf[ni]),
              acc[mi][ni], 0, 0, 0);
    }
    __syncthreads();
  }
  float s[4], ss[4];
  #pragma unroll
  for(int ni = 0; ni < 4; ++ni){
    float a = 0.f, b = 0.f;
    #pragma unroll
    for(int mi = 0; mi < 8; ++mi)
      #pragma unroll
      for(int j = 0; j < 4; ++j){
        float v = acc[mi][ni][j];
        a += v; b += v * v;
      }
    a += __shfl_xor(a, 16); a += __shfl_xor(a, 32);
    b += __shfl_xor(b, 16); b += __shfl_xor(b, 32);
    s[ni] = a; ss[ni] = b;
  }
  if(kh == 0){
    #pragma unroll
    for(int ni = 0; ni < 4; ++ni){
      int p = ni*16 + kl;
      ps[wid][p] = s[ni]; pss[wid][p] = ss[ni];
    }
  }
  __syncthreads();
  float mean[4], rstd[4];
  #pragma unroll
  for(int ni = 0; ni < 4; ++ni){
    int p = ni*16 + kl;
    float tot  = ps[0][p] + ps[1][p] + ps[2][p] + ps[3][p];
    float tots = pss[0][p] + pss[1][p] + pss[2][p] + pss[3][p];
    float m = tot * (1.0f/512.0f);
    mean[ni] = m;
    rstd[ni] = rsqrtf(tots * (1.0f/512.0f) - m*m + 1e-5f);
  }
  float* op = outp + (size_t)bl * CCH * HW;
  #pragma unroll
  for(int mi = 0; mi < 8; ++mi){
    int o = wid*128 + mi*16 + kh * 4;
    #pragma unroll
    for(int ni = 0; ni < 4; ++ni){
      int p = p0 + ni*16 + kl;
      #pragma unroll
      for(int j = 0; j < 4; ++j)
        op[(size_t)(o + j) * HW + p] = (acc[mi][ni][j] - mean[ni]) * rstd[ni] * gsh[o + j];
    }
  }
}

// ---- K7: dw3x3(K,V) fused + ctx partial via MFMA (fp16 in, f32 acc). 8 p-slices. ----
// Double-buffered ek/vv: ONE barrier per iteration (write buf[it&1] -> barrier -> MFMA).
__global__ __launch_bounds__(256)
void ctx_kernel(const unsigned short* __restrict__ Kq, const unsigned short* __restrict__ Vq,
                float* __restrict__ ctxp, float* __restrict__ ksp,
                const float* __restrict__ k_dw, const float* __restrict__ v_dw){
  __shared__ unsigned short ek[2][64][64];   // exp(k') f16, [d][p] XOR-swizzled
  __shared__ unsigned short vv[2][64][64];   // v' f16,     [e][p] XOR-swizzled
  __shared__ float wtk[9][68], wtv[9][68];
  __shared__ float ksred[16][68];
  int bh = blockIdx.x, sl = blockIdx.y;
  int bl = bh >> 3, h = bh & 7;
  int t = threadIdx.x, lane = t & 63, wid = t >> 6;
  int wr = wid >> 1, wc = wid & 1;
  int dq = t >> 4, j = t & 15, x4 = j * 4;
  int d0 = dq * 4;
  int kl = lane & 15, kh = lane >> 4;
  const unsigned short* kq = Kq + ((size_t)(bl*128 + h*16 + dq)) * HW * 4;
  const unsigned short* vq = Vq + ((size_t)(bl*128 + h*16 + dq)) * HW * 4;
  for(int i = t; i < 576; i += 256){
    int d = i / 9, tp = i % 9;
    wtk[tp][d] = k_dw[(size_t)(h*64 + d)*9 + tp];
    wtv[tp][d] = v_dw[(size_t)(h*64 + d)*9 + tp];
  }
  __syncthreads();
  f4 acc[2][2] = {};
  f4 ksacc = {0,0,0,0};
  const f4 zf = {0,0,0,0};
  for(int it = 0; it < 8; ++it){
    int cb = it & 1;
    int row = sl * 8 + it;
    f4 ok_[4] = {zf, zf, zf, zf}, ov_[4] = {zf, zf, zf, zf};
    #pragma unroll
    for(int dy = 0; dy < 3; ++dy){
      int r = row + dy - 1;
      if(r >= 0 && r < 64){
        f4 in[6];
        #pragma unroll
        for(int px = 0; px < 6; ++px){
          int x = x4 - 1 + px;
          in[px] = (x >= 0 && x < 64) ? ld_bf4(kq + ((size_t)r*64 + x)*4) : zf;
        }
        #pragma unroll
        for(int dx = 0; dx < 3; ++dx){
          f4 w = *(const f4*)&wtk[dy*3+dx][d0];
          #pragma unroll
          for(int xo = 0; xo < 4; ++xo) ok_[xo] += w * in[xo + dx];
        }
        #pragma unroll
        for(int px = 0; px < 6; ++px){
          int x = x4 - 1 + px;
          in[px] = (x >= 0 && x < 64) ? ld_bf4(vq + ((size_t)r*64 + x)*4) : zf;
        }
        #pragma unroll
        for(int dx = 0; dx < 3; ++dx){
          f4 w = *(const f4*)&wtv[dy*3+dx][d0];
          #pragma unroll
          for(int xo = 0; xo < 4; ++xo) ov_[xo] += w * in[xo + dx];
        }
      }
    }
    #pragma unroll
    for(int dd = 0; dd < 4; ++dd){
      int d = d0 + dd;
      int col = (((j >> 1) ^ (d & 7)) << 3) | ((j & 1) << 2);
      ushort4 pe, pv;
      unsigned short eh[4];
      #pragma unroll
      for(int xo = 0; xo < 4; ++xo){
        float ev = __expf(ok_[xo][dd]);
        _Float16 hv = (_Float16)ev;
        ksacc[dd] += (float)hv;          // ks from identically-rounded exp values
        eh[xo] = __builtin_bit_cast(unsigned short, hv);
      }
      pe.x = eh[0]; pe.y = eh[1]; pe.z = eh[2]; pe.w = eh[3];
      pv.x = f2h(ov_[0][dd]); pv.y = f2h(ov_[1][dd]);
      pv.z = f2h(ov_[2][dd]); pv.w = f2h(ov_[3][dd]);
      *(ushort4*)&ek[cb][d][col] = pe;
      *(ushort4*)&vv[cb][d][col] = pv;
    }
    __syncthreads();
    #pragma unroll
    for(int kk = 0; kk < 64; kk += 32){
      int g = (kk >> 3) + kh;
      short8 af[2], bfr[2];
      #pragma unroll
      for(int mi = 0; mi < 2; ++mi){
        int rowa = wr*32 + mi*16 + kl;
        af[mi] = *(const short8*)&ek[cb][rowa][((g ^ (rowa & 7)) << 3)];
      }
      #pragma unroll
      for(int ni = 0; ni < 2; ++ni){
        int rowb = wc*32 + ni*16 + kl;
        bfr[ni] = *(const short8*)&vv[cb][rowb][((g ^ (rowb & 7)) << 3)];
      }
      #pragma unroll
      for(int mi = 0; mi < 2; ++mi)
        #pragma unroll
        for(int ni = 0; ni < 2; ++ni)
          acc[mi][ni] = __builtin_amdgcn_mfma_f32_16x16x32_f16(
              __builtin_bit_cast(half8, af[mi]), __builtin_bit_cast(half8, bfr[ni]),
              acc[mi][ni], 0, 0, 0);
    }
  }
  // C/D layout: col=lane&15 -> e, row=(lane>>4)*4+jj -> d within tile
  float* cp = ctxp + ((size_t)bh * 8 + sl) * 4096;
  #pragma unroll
  for(int mi = 0; mi < 2; ++mi){
    int dbase = wr*32 + mi*16 + kh*4;
    #pragma unroll
    for(int ni = 0; ni < 2; ++ni){
      int e = wc*32 + ni*16 + kl;
      #pragma unroll
      for(int jj = 0; jj < 4; ++jj)
        cp[(size_t)(dbase + jj) * 64 + e] = acc[mi][ni][jj];
    }
  }
  __syncthreads();
  *(f4*)&ksred[j][d0] = ksacc;
  __syncthreads();
  if(t < 64){
    float s = 0.f;
    #pragma unroll
    for(int jj = 0; jj < 16; ++jj) s += ksred[jj][t];
    ksp[((size_t)bh * 8 + sl) * 64 + t] = s;
  }
}

// ---- K7b: reduce 8 ctx partials + normalize ----
__global__ __launch_bounds__(256)
void ctx_reduce_kernel(const float* __restrict__ ctxp, const float* __restrict__ ksp,
                       float* __restrict__ ctxf){
  __shared__ float kinv[64];
  int bh = blockIdx.x;
  int t = threadIdx.x;
  if(t < 64){
    const float* kp = ksp + (size_t)bh * 8 * 64;
    float s = 0.f;
    #pragma unroll
    for(int sl = 0; sl < 8; ++sl) s += kp[sl*64 + t];
    kinv[t] = 1.0f / s;
  }
  __syncthreads();
  const float* cp = ctxp + (size_t)bh * 8 * 4096;
  float* cf = ctxf + (size_t)bh * 4096;
  for(int i = t; i < 4096; i += 256){
    float s = 0.f;
    #pragma unroll
    for(int sl = 0; sl < 8; ++sl) s += cp[sl*4096 + i];
    cf[i] = s * kinv[i >> 6];
  }
}

// ---- K8: dw3x3(Q) + softmax_d + MFMA out = q_sm·ctx + silu -> fp16 att[p][c] ----
__global__ __launch_bounds__(256)
void att2_kernel(const unsigned short* __restrict__ Qq, const float* __restrict__ ctxf,
                 const float* __restrict__ q_dw,
                 unsigned short* __restrict__ att){
  __shared__ float qs[64][132];               // conv-Q output, [d][p] f32
  __shared__ unsigned short qb[128][68];      // softmaxed q, [p][d] bf16 (B-operand)
  __shared__ unsigned short ctxb[64][68];     // ctx, [e][d] bf16 (A-operand)
  int bidx = blockIdx.x;
  int chunk = (bidx & 31) * 128;
  int bh = bidx >> 5;
  int bl = bh >> 3, h = bh & 7;
  int t = threadIdx.x, lane = t & 63, wid = t >> 6;
  // ctx load (global [d][e] f32 -> LDS [e][d] bf16)
  const float* cb = ctxf + (size_t)bh * 4096;
  for(int i = t; i < 4096; i += 256)
    ctxb[i & 63][i >> 6] = f2bf(cb[i]);
  // conv-Q from quad layout
  {
    int dq = t >> 4, j = t & 15;
    int d0 = dq * 4;
    int row = (chunk >> 6) + (j >> 3), x8 = (j & 7) * 8;
    const unsigned short* qbp = Qq + ((size_t)(bl*128 + h*16 + dq)) * HW * 4;
    f4 wq[9];
    #pragma unroll
    for(int tp = 0; tp < 9; ++tp)
      #pragma unroll
      for(int dd = 0; dd < 4; ++dd)
        wq[tp][dd] = q_dw[(size_t)(h*64 + d0 + dd)*9 + tp];
    const f4 zf = {0,0,0,0};
    f4 out[8] = {zf, zf, zf, zf, zf, zf, zf, zf};
    #pragma unroll
    for(int dy = 0; dy < 3; ++dy){
      int r = row + dy - 1;
      if(r >= 0 && r < 64){
        f4 in[10];
        #pragma unroll
        for(int px = 0; px < 10; ++px){
          int x = x8 - 1 + px;
          f4 v = zf;
          if(x >= 0 && x < 64) v = ld_bf4(qbp + ((size_t)r*64 + x)*4);
          in[px] = v;
        }
        #pragma unroll
        for(int dx = 0; dx < 3; ++dx){
          f4 w = wq[dy*3+dx];
          #pragma unroll
          for(int xo = 0; xo < 8; ++xo)
            out[xo] += w * in[xo + dx];
        }
      }
    }
    #pragma unroll
    for(int xo = 0; xo < 8; ++xo)
      #pragma unroll
      for(int dd = 0; dd < 4; ++dd)
        qs[d0 + dd][j*8 + xo] = out[xo][dd];
  }
  __syncthreads();
  // softmax over d per pixel + bf16 convert -> qb[p][d]
  {
    int p = t >> 1, half = t & 1;
    float mx = -1e30f;
    #pragma unroll
    for(int jj = 0; jj < 32; ++jj) mx = fmaxf(mx, qs[half*32 + jj][p]);
    mx = fmaxf(mx, __shfl_xor(mx, 1));
    float s = 0.f;
    #pragma unroll
    for(int jj = 0; jj < 32; ++jj) s += __expf(qs[half*32 + jj][p] - mx);
    s += __shfl_xor(s, 1);
    float inv = 0.125f / s;
    #pragma unroll
    for(int jj = 0; jj < 16; ++jj){
      int d = half*32 + jj*2;
      float v0 = __expf(qs[d][p]     - mx) * inv;
      float v1 = __expf(qs[d + 1][p] - mx) * inv;
      unsigned pk = (unsigned)f2bf(v0) | ((unsigned)f2bf(v1) << 16);
      *(unsigned*)&qb[p][d] = pk;
    }
  }
  __syncthreads();
  // MFMA: out[e][p] = sum_d ctx[e][d]*q[p][d]; wave w owns p rows w*32..w*32+31
  f4 acc[4][2] = {};
  #pragma unroll
  for(int et = 0; et < 4; ++et){
    short8 a0 = *(const short8*)&ctxb[et*16 + (lane & 15)][(lane >> 4) * 8];
    short8 a1 = *(const short8*)&ctxb[et*16 + (lane & 15)][32 + (lane >> 4) * 8];
    #pragma unroll
    for(int pt = 0; pt < 2; ++pt){
      int prow = wid*32 + pt*16 + (lane & 15);
      short8 b0 = *(const short8*)&qb[prow][(lane >> 4) * 8];
      short8 b1 = *(const short8*)&qb[prow][32 + (lane >> 4) * 8];
      acc[et][pt] = __builtin_amdgcn_mfma_f32_16x16x32_bf16(a0, b0, acc[et][pt], 0, 0, 0);
      acc[et][pt] = __builtin_amdgcn_mfma_f32_16x16x32_bf16(a1, b1, acc[et][pt], 0, 0, 0);
    }
  }
  // silu + fp16 pack + store (C/D: col=lane&15 -> p, row=(lane>>4)*4+j -> e)
  #pragma unroll
  for(int et = 0; et < 4; ++et){
    int e0 = et*16 + (lane >> 4) * 4;
    #pragma unroll
    for(int pt = 0; pt < 2; ++pt){
      int p = chunk + wid*32 + pt*16 + (lane & 15);
      unsigned short hv[4];
      #pragma unroll
      for(int j = 0; j < 4; ++j){
        float x = acc[et][pt][j];
        hv[j] = f2h(x / (1.f + __expf(-x)));
      }
      uint2 pk;
      pk.x = (unsigned)hv[0] | ((unsigned)hv[1] << 16);
      pk.y = (unsigned)hv[2] | ((unsigned)hv[3] << 16);
      *(uint2*)(att + ((size_t)bl * HW + p) * CCH + h*64 + e0) = pk;
    }
  }
}

extern "C" void kernel_launch(void* const* d_in, const int* in_sizes, int n_in,
                              void* d_out, int out_size, void* d_ws, size_t ws_size,
                              hipStream_t stream){
  const float* fmap   = (const float*)d_in[0];
  const float* g_norm = (const float*)d_in[1];
  const float* q_w1   = (const float*)d_in[2];
  const float* q_dw   = (const float*)d_in[3];
  const float* k_w1   = (const float*)d_in[4];
  const float* k_dw   = (const float*)d_in[5];
  const float* v_w1   = (const float*)d_in[6];
  const float* v_dw   = (const float*)d_in[7];
  const float* out_w  = (const float*)d_in[8];
  const float* g_out  = (const float*)d_in[9];
  float* outp = (float*)d_out;

  const size_t WQKV = 1536*512*2;
  const size_t WOUT = 512*512*2;
  const size_t PERB = 19038208ull;
  int G = 16;
  while(G > 1 && (WQKV + WOUT + (size_t)G*PERB) > ws_size) G >>= 1;
  if((WQKV + WOUT + (size_t)G*PERB) > ws_size) return;

  char* w = (char*)d_ws;
  unsigned short* wqkv = (unsigned short*)w;
  unsigned short* wout = (unsigned short*)(w + WQKV);
  char* gb = w + WQKV + WOUT;
  unsigned short* xt  = (unsigned short*)gb;
  unsigned short* Qb  = (unsigned short*)(gb + (size_t)G *  4194304);
  float* ctxp = (float*)(gb + (size_t)G * 16777216);
  float* ksp  = (float*)(gb + (size_t)G * 18874368);
  float* ctxf = (float*)(gb + (size_t)G * 18907136);
  unsigned short* Kb = Qb + (size_t)G * CCH * HW;
  unsigned short* Vb = Kb + (size_t)G * CCH * HW;

  wsplit_bf_kernel<<<1024, 256, 0, stream>>>(q_w1, wqkv,          262144);
  wsplit_bf_kernel<<<1024, 256, 0, stream>>>(k_w1, wqkv + 262144, 262144);
  wsplit_bf_kernel<<<1024, 256, 0, stream>>>(v_w1, wqkv + 524288, 262144);
  wsplit_h_kernel <<<1024, 256, 0, stream>>>(out_w, wout,         262144);

  for(int b0 = 0; b0 < 16; b0 += G){
    const float* fg = fmap + (size_t)b0 * CCH * HW;
    float* og = outp + (size_t)b0 * CCH * HW;
    ln_tr_fused<<<G*128, 256, 0, stream>>>(fg, g_norm, xt);
    gemm_bt_kernel<<<dim3(32,12,G), 256, 0, stream>>>(wqkv, xt, Qb, (size_t)G * CCH * HW);
    ctx_kernel<<<dim3(G*8,8), 256, 0, stream>>>(Kb, Vb, ctxp, ksp, k_dw, v_dw);
    ctx_reduce_kernel<<<G*8, 256, 0, stream>>>(ctxp, ksp, ctxf);
    att2_kernel<<<G*256, 256, 0, stream>>>(Qb, ctxf, q_dw, xt);
    outln_kernel<<<dim3(64, G), 256, 0, stream>>>(wout, xt, g_out, og);
  }
}

// Round 10
// 386.086 us; speedup vs baseline: 1.2755x; 1.2755x over previous
//
#include <hip/hip_runtime.h>

#define CCH 512
#define HW  4096

typedef __attribute__((ext_vector_type(8))) short short8;
typedef __attribute__((ext_vector_type(8))) _Float16 half8;
typedef __attribute__((ext_vector_type(4))) float f4;

__device__ __forceinline__ unsigned short f2bf(float x){
  unsigned u = __builtin_bit_cast(unsigned, x);
  u += 0x7FFFu + ((u >> 16) & 1u);
  return (unsigned short)(u >> 16);
}
__device__ __forceinline__ float bf2f(unsigned short h){
  unsigned u = ((unsigned)h) << 16;
  return __builtin_bit_cast(float, u);
}
__device__ __forceinline__ unsigned short f2h(float x){
  _Float16 h = (_Float16)x;
  return __builtin_bit_cast(unsigned short, h);
}
__device__ __forceinline__ f4 ld_bf4(const unsigned short* p){
  ushort4 u = *(const ushort4*)p;
  f4 r; r[0]=bf2f(u.x); r[1]=bf2f(u.y); r[2]=bf2f(u.z); r[3]=bf2f(u.w);
  return r;
}
__device__ __forceinline__ f4 shfl_xor4(f4 v, int mask){
  f4 r;
  #pragma unroll
  for(int k = 0; k < 4; ++k) r[k] = __shfl_xor(v[k], mask);
  return r;
}

// ---- K0a/K0b: weight dtype conversion ----
__global__ void wsplit_bf_kernel(const float* __restrict__ src,
                                 unsigned short* __restrict__ dst, int n){
  int i = blockIdx.x * 256 + threadIdx.x;
  if(i < n) dst[i] = f2bf(src[i]);
}
__global__ void wsplit_h_kernel(const float* __restrict__ src,
                                unsigned short* __restrict__ dst, int n){
  int i = blockIdx.x * 256 + threadIdx.x;
  if(i < n) dst[i] = f2h(src[i]);
}

// ---- K2: fused LN stats + apply + transpose -> bf16 xt[p][c]. Block = 32 px x 512 c. ----
__global__ __launch_bounds__(256)
void ln_tr_fused(const float* __restrict__ x, const float* __restrict__ g,
                 unsigned short* __restrict__ xt){
  __shared__ unsigned short xs[512][32];
  __shared__ float gln[512];
  __shared__ f4 red_s[4][8], red_ss[4][8];
  __shared__ float sm[32], sr[32];
  int pix0 = blockIdx.x * 32;
  int bl = pix0 >> 12, p0 = pix0 & 4095;
  int t = threadIdx.x, lane = t & 63, wid = t >> 6;
  gln[t] = g[t]; gln[t + 256] = g[t + 256];
  int j = t & 7;
  f4 s4 = {0,0,0,0}, ss4 = {0,0,0,0};
  for(int ci = t >> 3; ci < 512; ci += 32){
    f4 v = *(const f4*)(x + ((size_t)(bl*512 + ci)) * HW + p0 + j*4);
    s4 += v; ss4 += v * v;
    ushort4 b;
    b.x = f2bf(v[0]); b.y = f2bf(v[1]); b.z = f2bf(v[2]); b.w = f2bf(v[3]);
    *(ushort4*)&xs[ci][j*4] = b;
  }
  #pragma unroll
  for(int m = 8; m < 64; m <<= 1){ s4 += shfl_xor4(s4, m); ss4 += shfl_xor4(ss4, m); }
  if((lane >> 3) == 0){ red_s[wid][j] = s4; red_ss[wid][j] = ss4; }
  __syncthreads();
  if(t < 32){
    int jj = t >> 2, k = t & 3;
    const float* rs = (const float*)red_s;
    const float* rss = (const float*)red_ss;
    float s = 0.f, ss = 0.f;
    #pragma unroll
    for(int w = 0; w < 4; ++w){ s += rs[(w*8 + jj)*4 + k]; ss += rss[(w*8 + jj)*4 + k]; }
    float m = s * (1.0f/512.0f);
    float var = ss * (1.0f/512.0f) - m*m;
    sm[t] = m; sr[t] = rsqrtf(var + 1e-5f);
  }
  __syncthreads();
  int px = t & 31, cs = t >> 5;
  float m = sm[px], r = sr[px];
  for(int i = 0; i < 8; ++i){
    int c0 = cs * 64 + i * 8;
    short8 o;
    #pragma unroll
    for(int k = 0; k < 8; ++k){
      float f = bf2f(xs[c0 + k][px]);
      o[k] = (short)f2bf((f - m) * r * gln[c0 + k]);
    }
    *(short8*)(xt + ((size_t)(pix0 + px)) * 512 + c0) = o;
  }
}

// ---- K3: QKV GEMM (gll staging, XOR-swizzled LDS, 64x64 wave tile, 3 blocks/CU) ----
__global__ __launch_bounds__(256, 2)
void gemm_bt_kernel(const unsigned short* __restrict__ A,
                    const unsigned short* __restrict__ B,
                    unsigned short* __restrict__ Out, size_t bufStride){
  __shared__ unsigned short sA[128][64], sB[128][64];
  int bl = blockIdx.z;
  const unsigned short* bsrc = B + (size_t)bl * HW * CCH;
  int p0 = blockIdx.x * 128;
  int oA = blockIdx.y * 128;
  int o0 = (blockIdx.y & 3) * 128;
  int buf = blockIdx.y >> 2;
  int t = threadIdx.x, lane = t & 63, wid = t >> 6;
  int wr = wid >> 1, wc = wid & 1;
  int srow  = lane >> 3;
  int scol8 = ((lane & 7) ^ srow) * 8;
  f4 acc[4][4] = {};
  for(int k0 = 0; k0 < CCH; k0 += 64){
    #pragma unroll
    for(int i = 0; i < 4; ++i){
      int r = wid * 32 + i * 8;
      const unsigned short* gA = A    + (size_t)(oA + r + srow) * CCH + k0 + scol8;
      const unsigned short* gB = bsrc + (size_t)(p0 + r + srow) * CCH + k0 + scol8;
      __builtin_amdgcn_global_load_lds(
          (const __attribute__((address_space(1))) void*)gA,
          (__attribute__((address_space(3))) void*)&sA[r][0], 16, 0, 0);
      __builtin_amdgcn_global_load_lds(
          (const __attribute__((address_space(1))) void*)gB,
          (__attribute__((address_space(3))) void*)&sB[r][0], 16, 0, 0);
    }
    __syncthreads();
    #pragma unroll
    for(int kk = 0; kk < 64; kk += 32){
      int ka = kk + (lane >> 4) * 8;
      short8 af[4], bf[4];
      #pragma unroll
      for(int mi = 0; mi < 4; ++mi){
        int row = wr*64 + mi*16 + (lane & 15);
        af[mi] = *(const short8*)&sA[row][(((ka >> 3) ^ (row & 7)) * 8)];
      }
      #pragma unroll
      for(int ni = 0; ni < 4; ++ni){
        int row = wc*64 + ni*16 + (lane & 15);
        bf[ni] = *(const short8*)&sB[row][(((ka >> 3) ^ (row & 7)) * 8)];
      }
      #pragma unroll
      for(int mi = 0; mi < 4; ++mi)
        #pragma unroll
        for(int ni = 0; ni < 4; ++ni)
          acc[mi][ni] = __builtin_amdgcn_mfma_f32_16x16x32_bf16(af[mi], bf[ni], acc[mi][ni], 0, 0, 0);
    }
    __syncthreads();
  }
  unsigned short* op = Out + (size_t)buf * bufStride + (size_t)bl * CCH * HW;
  #pragma unroll
  for(int mi = 0; mi < 4; ++mi){
    int oq = (o0 + wr*64 + mi*16) / 4 + (lane >> 4);
    #pragma unroll
    for(int ni = 0; ni < 4; ++ni){
      int p = p0 + wc*64 + ni*16 + (lane & 15);
      uint2 pk;
      pk.x = (unsigned)f2bf(acc[mi][ni][0]) | ((unsigned)f2bf(acc[mi][ni][1]) << 16);
      pk.y = (unsigned)f2bf(acc[mi][ni][2]) | ((unsigned)f2bf(acc[mi][ni][3]) << 16);
      *(uint2*)(op + ((size_t)oq * HW + p) * 4) = pk;
    }
  }
}

// ---- K6: fused out-GEMM + final LN. Tile 512(ch) x 64(px), 256 thr, 2 blocks/CU. ----
__global__ __launch_bounds__(256, 2)
void outln_kernel(const unsigned short* __restrict__ W, const unsigned short* __restrict__ att,
                  const float* __restrict__ g, float* __restrict__ outp){
  __shared__ unsigned short sA[512][64], sB[64][64];
  __shared__ float ps[4][64], pss[4][64];
  __shared__ float gsh[512];
  int bl = blockIdx.y;
  int p0 = blockIdx.x * 64;
  const unsigned short* bsrc = att + (size_t)bl * HW * CCH;
  int t = threadIdx.x, lane = t & 63, wid = t >> 6;
  int kl = lane & 15, kh = lane >> 4;
  int srow  = lane >> 3;
  int scol8 = ((lane & 7) ^ srow) * 8;
  gsh[t] = g[t]; gsh[t + 256] = g[t + 256];
  f4 acc[8][4] = {};
  for(int kt = 0; kt < 8; ++kt){
    int k0 = kt * 64;
    #pragma unroll
    for(int i = 0; i < 16; ++i){
      int r = wid * 128 + i * 8;
      const unsigned short* gA = W + (size_t)(r + srow) * CCH + k0 + scol8;
      __builtin_amdgcn_global_load_lds(
          (const __attribute__((address_space(1))) void*)gA,
          (__attribute__((address_space(3))) void*)&sA[r][0], 16, 0, 0);
    }
    #pragma unroll
    for(int i = 0; i < 2; ++i){
      int r = wid * 16 + i * 8;
      const unsigned short* gB = bsrc + (size_t)(p0 + r + srow) * CCH + k0 + scol8;
      __builtin_amdgcn_global_load_lds(
          (const __attribute__((address_space(1))) void*)gB,
          (__attribute__((address_space(3))) void*)&sB[r][0], 16, 0, 0);
    }
    __syncthreads();
    #pragma unroll
    for(int kk = 0; kk < 64; kk += 32){
      int ka = kk + kh * 8;
      short8 af[8], bf[4];
      #pragma unroll
      for(int mi = 0; mi < 8; ++mi){
        int row = wid*128 + mi*16 + kl;
        af[mi] = *(const short8*)&sA[row][(((ka >> 3) ^ (row & 7)) * 8)];
      }
      #pragma unroll
      for(int ni = 0; ni < 4; ++ni){
        int row = ni*16 + kl;
        bf[ni] = *(const short8*)&sB[row][(((ka >> 3) ^ (row & 7)) * 8)];
      }
      #pragma unroll
      for(int mi = 0; mi < 8; ++mi)
        #pragma unroll
        for(int ni = 0; ni < 4; ++ni)
          acc[mi][ni] = __builtin_amdgcn_mfma_f32_16x16x32_f16(
              __builtin_bit_cast(half8, af[mi]), __builtin_bit_cast(half8, bf[ni]),
              acc[mi][ni], 0, 0, 0);
    }
    __syncthreads();
  }
  float s[4], ss[4];
  #pragma unroll
  for(int ni = 0; ni < 4; ++ni){
    float a = 0.f, b = 0.f;
    #pragma unroll
    for(int mi = 0; mi < 8; ++mi)
      #pragma unroll
      for(int j = 0; j < 4; ++j){
        float v = acc[mi][ni][j];
        a += v; b += v * v;
      }
    a += __shfl_xor(a, 16); a += __shfl_xor(a, 32);
    b += __shfl_xor(b, 16); b += __shfl_xor(b, 32);
    s[ni] = a; ss[ni] = b;
  }
  if(kh == 0){
    #pragma unroll
    for(int ni = 0; ni < 4; ++ni){
      int p = ni*16 + kl;
      ps[wid][p] = s[ni]; pss[wid][p] = ss[ni];
    }
  }
  __syncthreads();
  float mean[4], rstd[4];
  #pragma unroll
  for(int ni = 0; ni < 4; ++ni){
    int p = ni*16 + kl;
    float tot  = ps[0][p] + ps[1][p] + ps[2][p] + ps[3][p];
    float tots = pss[0][p] + pss[1][p] + pss[2][p] + pss[3][p];
    float m = tot * (1.0f/512.0f);
    mean[ni] = m;
    rstd[ni] = rsqrtf(tots * (1.0f/512.0f) - m*m + 1e-5f);
  }
  float* op = outp + (size_t)bl * CCH * HW;
  #pragma unroll
  for(int mi = 0; mi < 8; ++mi){
    int o = wid*128 + mi*16 + kh * 4;
    #pragma unroll
    for(int ni = 0; ni < 4; ++ni){
      int p = p0 + ni*16 + kl;
      #pragma unroll
      for(int j = 0; j < 4; ++j)
        op[(size_t)(o + j) * HW + p] = (acc[mi][ni][j] - mean[ni]) * rstd[ni] * gsh[o + j];
    }
  }
}

// ---- K7: dw3x3(K,V) fused + ctx partial via MFMA (fp16 in, f32 acc). 8 p-slices. ----
// Double-buffered ek/vv: ONE barrier per iteration (write buf[it&1] -> barrier -> MFMA).
__global__ __launch_bounds__(256)
void ctx_kernel(const unsigned short* __restrict__ Kq, const unsigned short* __restrict__ Vq,
                float* __restrict__ ctxp, float* __restrict__ ksp,
                const float* __restrict__ k_dw, const float* __restrict__ v_dw){
  __shared__ unsigned short ek[2][64][64];   // exp(k') f16, [d][p] XOR-swizzled
  __shared__ unsigned short vv[2][64][64];   // v' f16,     [e][p] XOR-swizzled
  __shared__ float wtk[9][68], wtv[9][68];
  __shared__ float ksred[16][68];
  int bh = blockIdx.x, sl = blockIdx.y;
  int bl = bh >> 3, h = bh & 7;
  int t = threadIdx.x, lane = t & 63, wid = t >> 6;
  int wr = wid >> 1, wc = wid & 1;
  int dq = t >> 4, j = t & 15, x4 = j * 4;
  int d0 = dq * 4;
  int kl = lane & 15, kh = lane >> 4;
  const unsigned short* kq = Kq + ((size_t)(bl*128 + h*16 + dq)) * HW * 4;
  const unsigned short* vq = Vq + ((size_t)(bl*128 + h*16 + dq)) * HW * 4;
  for(int i = t; i < 576; i += 256){
    int d = i / 9, tp = i % 9;
    wtk[tp][d] = k_dw[(size_t)(h*64 + d)*9 + tp];
    wtv[tp][d] = v_dw[(size_t)(h*64 + d)*9 + tp];
  }
  __syncthreads();
  f4 acc[2][2] = {};
  f4 ksacc = {0,0,0,0};
  const f4 zf = {0,0,0,0};
  for(int it = 0; it < 8; ++it){
    int cb = it & 1;
    int row = sl * 8 + it;
    f4 ok_[4] = {zf, zf, zf, zf}, ov_[4] = {zf, zf, zf, zf};
    #pragma unroll
    for(int dy = 0; dy < 3; ++dy){
      int r = row + dy - 1;
      if(r >= 0 && r < 64){
        f4 in[6];
        #pragma unroll
        for(int px = 0; px < 6; ++px){
          int x = x4 - 1 + px;
          in[px] = (x >= 0 && x < 64) ? ld_bf4(kq + ((size_t)r*64 + x)*4) : zf;
        }
        #pragma unroll
        for(int dx = 0; dx < 3; ++dx){
          f4 w = *(const f4*)&wtk[dy*3+dx][d0];
          #pragma unroll
          for(int xo = 0; xo < 4; ++xo) ok_[xo] += w * in[xo + dx];
        }
        #pragma unroll
        for(int px = 0; px < 6; ++px){
          int x = x4 - 1 + px;
          in[px] = (x >= 0 && x < 64) ? ld_bf4(vq + ((size_t)r*64 + x)*4) : zf;
        }
        #pragma unroll
        for(int dx = 0; dx < 3; ++dx){
          f4 w = *(const f4*)&wtv[dy*3+dx][d0];
          #pragma unroll
          for(int xo = 0; xo < 4; ++xo) ov_[xo] += w * in[xo + dx];
        }
      }
    }
    #pragma unroll
    for(int dd = 0; dd < 4; ++dd){
      int d = d0 + dd;
      int col = (((j >> 1) ^ (d & 7)) << 3) | ((j & 1) << 2);
      ushort4 pe, pv;
      unsigned short eh[4];
      #pragma unroll
      for(int xo = 0; xo < 4; ++xo){
        float ev = __expf(ok_[xo][dd]);
        _Float16 hv = (_Float16)ev;
        ksacc[dd] += (float)hv;          // ks from identically-rounded exp values
        eh[xo] = __builtin_bit_cast(unsigned short, hv);
      }
      pe.x = eh[0]; pe.y = eh[1]; pe.z = eh[2]; pe.w = eh[3];
      pv.x = f2h(ov_[0][dd]); pv.y = f2h(ov_[1][dd]);
      pv.z = f2h(ov_[2][dd]); pv.w = f2h(ov_[3][dd]);
      *(ushort4*)&ek[cb][d][col] = pe;
      *(ushort4*)&vv[cb][d][col] = pv;
    }
    __syncthreads();
    #pragma unroll
    for(int kk = 0; kk < 64; kk += 32){
      int g = (kk >> 3) + kh;
      short8 af[2], bfr[2];
      #pragma unroll
      for(int mi = 0; mi < 2; ++mi){
        int rowa = wr*32 + mi*16 + kl;
        af[mi] = *(const short8*)&ek[cb][rowa][((g ^ (rowa & 7)) << 3)];
      }
      #pragma unroll
      for(int ni = 0; ni < 2; ++ni){
        int rowb = wc*32 + ni*16 + kl;
        bfr[ni] = *(const short8*)&vv[cb][rowb][((g ^ (rowb & 7)) << 3)];
      }
      #pragma unroll
      for(int mi = 0; mi < 2; ++mi)
        #pragma unroll
        for(int ni = 0; ni < 2; ++ni)
          acc[mi][ni] = __builtin_amdgcn_mfma_f32_16x16x32_f16(
              __builtin_bit_cast(half8, af[mi]), __builtin_bit_cast(half8, bfr[ni]),
              acc[mi][ni], 0, 0, 0);
    }
  }
  // C/D layout: col=lane&15 -> e, row=(lane>>4)*4+jj -> d within tile
  float* cp = ctxp + ((size_t)bh * 8 + sl) * 4096;
  #pragma unroll
  for(int mi = 0; mi < 2; ++mi){
    int dbase = wr*32 + mi*16 + kh*4;
    #pragma unroll
    for(int ni = 0; ni < 2; ++ni){
      int e = wc*32 + ni*16 + kl;
      #pragma unroll
      for(int jj = 0; jj < 4; ++jj)
        cp[(size_t)(dbase + jj) * 64 + e] = acc[mi][ni][jj];
    }
  }
  __syncthreads();
  *(f4*)&ksred[j][d0] = ksacc;
  __syncthreads();
  if(t < 64){
    float s = 0.f;
    #pragma unroll
    for(int jj = 0; jj < 16; ++jj) s += ksred[jj][t];
    ksp[((size_t)bh * 8 + sl) * 64 + t] = s;
  }
}

// ---- K7b: reduce 8 ctx partials + normalize ----
__global__ __launch_bounds__(256)
void ctx_reduce_kernel(const float* __restrict__ ctxp, const float* __restrict__ ksp,
                       float* __restrict__ ctxf){
  __shared__ float kinv[64];
  int bh = blockIdx.x;
  int t = threadIdx.x;
  if(t < 64){
    const float* kp = ksp + (size_t)bh * 8 * 64;
    float s = 0.f;
    #pragma unroll
    for(int sl = 0; sl < 8; ++sl) s += kp[sl*64 + t];
    kinv[t] = 1.0f / s;
  }
  __syncthreads();
  const float* cp = ctxp + (size_t)bh * 8 * 4096;
  float* cf = ctxf + (size_t)bh * 4096;
  for(int i = t; i < 4096; i += 256){
    float s = 0.f;
    #pragma unroll
    for(int sl = 0; sl < 8; ++sl) s += cp[sl*4096 + i];
    cf[i] = s * kinv[i >> 6];
  }
}

// ---- K8: dw3x3(Q) + softmax_d + MFMA out = q_sm·ctx + silu -> fp16 att[p][c] ----
__global__ __launch_bounds__(256)
void att2_kernel(const unsigned short* __restrict__ Qq, const float* __restrict__ ctxf,
                 const float* __restrict__ q_dw,
                 unsigned short* __restrict__ att){
  __shared__ float qs[64][132];               // conv-Q output, [d][p] f32
  __shared__ unsigned short qb[128][68];      // softmaxed q, [p][d] bf16 (B-operand)
  __shared__ unsigned short ctxb[64][68];     // ctx, [e][d] bf16 (A-operand)
  int bidx = blockIdx.x;
  int chunk = (bidx & 31) * 128;
  int bh = bidx >> 5;
  int bl = bh >> 3, h = bh & 7;
  int t = threadIdx.x, lane = t & 63, wid = t >> 6;
  // ctx load (global [d][e] f32 -> LDS [e][d] bf16)
  const float* cb = ctxf + (size_t)bh * 4096;
  for(int i = t; i < 4096; i += 256)
    ctxb[i & 63][i >> 6] = f2bf(cb[i]);
  // conv-Q from quad layout
  {
    int dq = t >> 4, j = t & 15;
    int d0 = dq * 4;
    int row = (chunk >> 6) + (j >> 3), x8 = (j & 7) * 8;
    const unsigned short* qbp = Qq + ((size_t)(bl*128 + h*16 + dq)) * HW * 4;
    f4 wq[9];
    #pragma unroll
    for(int tp = 0; tp < 9; ++tp)
      #pragma unroll
      for(int dd = 0; dd < 4; ++dd)
        wq[tp][dd] = q_dw[(size_t)(h*64 + d0 + dd)*9 + tp];
    const f4 zf = {0,0,0,0};
    f4 out[8] = {zf, zf, zf, zf, zf, zf, zf, zf};
    #pragma unroll
    for(int dy = 0; dy < 3; ++dy){
      int r = row + dy - 1;
      if(r >= 0 && r < 64){
        f4 in[10];
        #pragma unroll
        for(int px = 0; px < 10; ++px){
          int x = x8 - 1 + px;
          f4 v = zf;
          if(x >= 0 && x < 64) v = ld_bf4(qbp + ((size_t)r*64 + x)*4);
          in[px] = v;
        }
        #pragma unroll
        for(int dx = 0; dx < 3; ++dx){
          f4 w = wq[dy*3+dx];
          #pragma unroll
          for(int xo = 0; xo < 8; ++xo)
            out[xo] += w * in[xo + dx];
        }
      }
    }
    #pragma unroll
    for(int xo = 0; xo < 8; ++xo)
      #pragma unroll
      for(int dd = 0; dd < 4; ++dd)
        qs[d0 + dd][j*8 + xo] = out[xo][dd];
  }
  __syncthreads();
  // softmax over d per pixel + bf16 convert -> qb[p][d]
  {
    int p = t >> 1, half = t & 1;
    float mx = -1e30f;
    #pragma unroll
    for(int jj = 0; jj < 32; ++jj) mx = fmaxf(mx, qs[half*32 + jj][p]);
    mx = fmaxf(mx, __shfl_xor(mx, 1));
    float s = 0.f;
    #pragma unroll
    for(int jj = 0; jj < 32; ++jj) s += __expf(qs[half*32 + jj][p] - mx);
    s += __shfl_xor(s, 1);
    float inv = 0.125f / s;
    #pragma unroll
    for(int jj = 0; jj < 16; ++jj){
      int d = half*32 + jj*2;
      float v0 = __expf(qs[d][p]     - mx) * inv;
      float v1 = __expf(qs[d + 1][p] - mx) * inv;
      unsigned pk = (unsigned)f2bf(v0) | ((unsigned)f2bf(v1) << 16);
      *(unsigned*)&qb[p][d] = pk;
    }
  }
  __syncthreads();
  // MFMA: out[e][p] = sum_d ctx[e][d]*q[p][d]; wave w owns p rows w*32..w*32+31
  f4 acc[4][2] = {};
  #pragma unroll
  for(int et = 0; et < 4; ++et){
    short8 a0 = *(const short8*)&ctxb[et*16 + (lane & 15)][(lane >> 4) * 8];
    short8 a1 = *(const short8*)&ctxb[et*16 + (lane & 15)][32 + (lane >> 4) * 8];
    #pragma unroll
    for(int pt = 0; pt < 2; ++pt){
      int prow = wid*32 + pt*16 + (lane & 15);
      short8 b0 = *(const short8*)&qb[prow][(lane >> 4) * 8];
      short8 b1 = *(const short8*)&qb[prow][32 + (lane >> 4) * 8];
      acc[et][pt] = __builtin_amdgcn_mfma_f32_16x16x32_bf16(a0, b0, acc[et][pt], 0, 0, 0);
      acc[et][pt] = __builtin_amdgcn_mfma_f32_16x16x32_bf16(a1, b1, acc[et][pt], 0, 0, 0);
    }
  }
  // silu + fp16 pack + store (C/D: col=lane&15 -> p, row=(lane>>4)*4+j -> e)
  #pragma unroll
  for(int et = 0; et < 4; ++et){
    int e0 = et*16 + (lane >> 4) * 4;
    #pragma unroll
    for(int pt = 0; pt < 2; ++pt){
      int p = chunk + wid*32 + pt*16 + (lane & 15);
      unsigned short hv[4];
      #pragma unroll
      for(int j = 0; j < 4; ++j){
        float x = acc[et][pt][j];
        hv[j] = f2h(x / (1.f + __expf(-x)));
      }
      uint2 pk;
      pk.x = (unsigned)hv[0] | ((unsigned)hv[1] << 16);
      pk.y = (unsigned)hv[2] | ((unsigned)hv[3] << 16);
      *(uint2*)(att + ((size_t)bl * HW + p) * CCH + h*64 + e0) = pk;
    }
  }
}

extern "C" void kernel_launch(void* const* d_in, const int* in_sizes, int n_in,
                              void* d_out, int out_size, void* d_ws, size_t ws_size,
                              hipStream_t stream){
  const float* fmap   = (const float*)d_in[0];
  const float* g_norm = (const float*)d_in[1];
  const float* q_w1   = (const float*)d_in[2];
  const float* q_dw   = (const float*)d_in[3];
  const float* k_w1   = (const float*)d_in[4];
  const float* k_dw   = (const float*)d_in[5];
  const float* v_w1   = (const float*)d_in[6];
  const float* v_dw   = (const float*)d_in[7];
  const float* out_w  = (const float*)d_in[8];
  const float* g_out  = (const float*)d_in[9];
  float* outp = (float*)d_out;

  const size_t WQKV = 1536*512*2;
  const size_t WOUT = 512*512*2;
  const size_t PERB = 19038208ull;
  int G = 16;
  while(G > 1 && (WQKV + WOUT + (size_t)G*PERB) > ws_size) G >>= 1;
  if((WQKV + WOUT + (size_t)G*PERB) > ws_size) return;

  char* w = (char*)d_ws;
  unsigned short* wqkv = (unsigned short*)w;
  unsigned short* wout = (unsigned short*)(w + WQKV);
  char* gb = w + WQKV + WOUT;
  unsigned short* xt  = (unsigned short*)gb;
  unsigned short* Qb  = (unsigned short*)(gb + (size_t)G *  4194304);
  float* ctxp = (float*)(gb + (size_t)G * 16777216);
  float* ksp  = (float*)(gb + (size_t)G * 18874368);
  float* ctxf = (float*)(gb + (size_t)G * 18907136);
  unsigned short* Kb = Qb + (size_t)G * CCH * HW;
  unsigned short* Vb = Kb + (size_t)G * CCH * HW;

  wsplit_bf_kernel<<<1024, 256, 0, stream>>>(q_w1, wqkv,          262144);
  wsplit_bf_kernel<<<1024, 256, 0, stream>>>(k_w1, wqkv + 262144, 262144);
  wsplit_bf_kernel<<<1024, 256, 0, stream>>>(v_w1, wqkv + 524288, 262144);
  wsplit_h_kernel <<<1024, 256, 0, stream>>>(out_w, wout,         262144);

  for(int b0 = 0; b0 < 16; b0 += G){
    const float* fg = fmap + (size_t)b0 * CCH * HW;
    float* og = outp + (size_t)b0 * CCH * HW;
    ln_tr_fused<<<G*128, 256, 0, stream>>>(fg, g_norm, xt);
    gemm_bt_kernel<<<dim3(32,12,G), 256, 0, stream>>>(wqkv, xt, Qb, (size_t)G * CCH * HW);
    ctx_kernel<<<dim3(G*8,8), 256, 0, stream>>>(Kb, Vb, ctxp, ksp, k_dw, v_dw);
    ctx_reduce_kernel<<<G*8, 256, 0, stream>>>(ctxp, ksp, ctxf);
    att2_kernel<<<G*256, 256, 0, stream>>>(Qb, ctxf, q_dw, xt);
    outln_kernel<<<dim3(64, G), 256, 0, stream>>>(wout, xt, g_out, og);
  }
}

// Round 11
// 370.428 us; speedup vs baseline: 1.3294x; 1.0423x over previous
//
#include <hip/hip_runtime.h>

#define CCH 512
#define HW  4096

typedef __attribute__((ext_vector_type(8))) short short8;
typedef __attribute__((ext_vector_type(8))) _Float16 half8;
typedef __attribute__((ext_vector_type(4))) float f4;

__device__ __forceinline__ unsigned short f2bf(float x){
  unsigned u = __builtin_bit_cast(unsigned, x);
  u += 0x7FFFu + ((u >> 16) & 1u);
  return (unsigned short)(u >> 16);
}
__device__ __forceinline__ float bf2f(unsigned short h){
  unsigned u = ((unsigned)h) << 16;
  return __builtin_bit_cast(float, u);
}
__device__ __forceinline__ unsigned short f2h(float x){
  _Float16 h = (_Float16)x;
  return __builtin_bit_cast(unsigned short, h);
}
__device__ __forceinline__ f4 ld_bf4(const unsigned short* p){
  ushort4 u = *(const ushort4*)p;
  f4 r; r[0]=bf2f(u.x); r[1]=bf2f(u.y); r[2]=bf2f(u.z); r[3]=bf2f(u.w);
  return r;
}
__device__ __forceinline__ f4 shfl_xor4(f4 v, int mask){
  f4 r;
  #pragma unroll
  for(int k = 0; k < 4; ++k) r[k] = __shfl_xor(v[k], mask);
  return r;
}

// ---- K0: fused weight dtype conversion (q/k/v -> bf16, out_w -> f16) ----
__global__ void wsplit_all_kernel(const float* __restrict__ q, const float* __restrict__ k,
                                  const float* __restrict__ v, const float* __restrict__ o,
                                  unsigned short* __restrict__ wqkv,
                                  unsigned short* __restrict__ wout){
  int i = blockIdx.x * 256 + threadIdx.x;     // 0 .. 4*262144-1
  int seg = i >> 18;
  int off = i & 262143;
  if(seg == 0)      wqkv[off]          = f2bf(q[off]);
  else if(seg == 1) wqkv[262144 + off] = f2bf(k[off]);
  else if(seg == 2) wqkv[524288 + off] = f2bf(v[off]);
  else              wout[off]          = f2h(o[off]);
}

// ---- K2: fused LN stats + apply + transpose -> bf16 xt[p][c]. Block = 32 px x 512 c.
// Also zero-fills the ctx/ks atomic accumulators (zbuf, zn floats) for this group. ----
__global__ __launch_bounds__(256)
void ln_tr_fused(const float* __restrict__ x, const float* __restrict__ g,
                 unsigned short* __restrict__ xt, float* __restrict__ zbuf, int zn){
  __shared__ unsigned short xs[512][32];
  __shared__ float gln[512];
  __shared__ f4 red_s[4][8], red_ss[4][8];
  __shared__ float sm[32], sr[32];
  int pix0 = blockIdx.x * 32;
  int bl = pix0 >> 12, p0 = pix0 & 4095;
  int t = threadIdx.x, lane = t & 63, wid = t >> 6;
  for(int i = blockIdx.x * 256 + t; i < zn; i += gridDim.x * 256) zbuf[i] = 0.f;
  gln[t] = g[t]; gln[t + 256] = g[t + 256];
  int j = t & 7;
  f4 s4 = {0,0,0,0}, ss4 = {0,0,0,0};
  for(int ci = t >> 3; ci < 512; ci += 32){
    f4 v = *(const f4*)(x + ((size_t)(bl*512 + ci)) * HW + p0 + j*4);
    s4 += v; ss4 += v * v;
    ushort4 b;
    b.x = f2bf(v[0]); b.y = f2bf(v[1]); b.z = f2bf(v[2]); b.w = f2bf(v[3]);
    *(ushort4*)&xs[ci][j*4] = b;
  }
  #pragma unroll
  for(int m = 8; m < 64; m <<= 1){ s4 += shfl_xor4(s4, m); ss4 += shfl_xor4(ss4, m); }
  if((lane >> 3) == 0){ red_s[wid][j] = s4; red_ss[wid][j] = ss4; }
  __syncthreads();
  if(t < 32){
    int jj = t >> 2, k = t & 3;
    const float* rs = (const float*)red_s;
    const float* rss = (const float*)red_ss;
    float s = 0.f, ss = 0.f;
    #pragma unroll
    for(int w = 0; w < 4; ++w){ s += rs[(w*8 + jj)*4 + k]; ss += rss[(w*8 + jj)*4 + k]; }
    float m = s * (1.0f/512.0f);
    float var = ss * (1.0f/512.0f) - m*m;
    sm[t] = m; sr[t] = rsqrtf(var + 1e-5f);
  }
  __syncthreads();
  int px = t & 31, cs = t >> 5;
  float m = sm[px], r = sr[px];
  for(int i = 0; i < 8; ++i){
    int c0 = cs * 64 + i * 8;
    short8 o;
    #pragma unroll
    for(int k = 0; k < 8; ++k){
      float f = bf2f(xs[c0 + k][px]);
      o[k] = (short)f2bf((f - m) * r * gln[c0 + k]);
    }
    *(short8*)(xt + ((size_t)(pix0 + px)) * 512 + c0) = o;
  }
}

// ---- K3: QKV GEMM (gll staging, XOR-swizzled LDS, 64x64 wave tile, 3 blocks/CU) ----
__global__ __launch_bounds__(256, 2)
void gemm_bt_kernel(const unsigned short* __restrict__ A,
                    const unsigned short* __restrict__ B,
                    unsigned short* __restrict__ Out, size_t bufStride){
  __shared__ unsigned short sA[128][64], sB[128][64];
  int bl = blockIdx.z;
  const unsigned short* bsrc = B + (size_t)bl * HW * CCH;
  int p0 = blockIdx.x * 128;
  int oA = blockIdx.y * 128;
  int o0 = (blockIdx.y & 3) * 128;
  int buf = blockIdx.y >> 2;
  int t = threadIdx.x, lane = t & 63, wid = t >> 6;
  int wr = wid >> 1, wc = wid & 1;
  int srow  = lane >> 3;
  int scol8 = ((lane & 7) ^ srow) * 8;
  f4 acc[4][4] = {};
  for(int k0 = 0; k0 < CCH; k0 += 64){
    #pragma unroll
    for(int i = 0; i < 4; ++i){
      int r = wid * 32 + i * 8;
      const unsigned short* gA = A    + (size_t)(oA + r + srow) * CCH + k0 + scol8;
      const unsigned short* gB = bsrc + (size_t)(p0 + r + srow) * CCH + k0 + scol8;
      __builtin_amdgcn_global_load_lds(
          (const __attribute__((address_space(1))) void*)gA,
          (__attribute__((address_space(3))) void*)&sA[r][0], 16, 0, 0);
      __builtin_amdgcn_global_load_lds(
          (const __attribute__((address_space(1))) void*)gB,
          (__attribute__((address_space(3))) void*)&sB[r][0], 16, 0, 0);
    }
    __syncthreads();
    #pragma unroll
    for(int kk = 0; kk < 64; kk += 32){
      int ka = kk + (lane >> 4) * 8;
      short8 af[4], bf[4];
      #pragma unroll
      for(int mi = 0; mi < 4; ++mi){
        int row = wr*64 + mi*16 + (lane & 15);
        af[mi] = *(const short8*)&sA[row][(((ka >> 3) ^ (row & 7)) * 8)];
      }
      #pragma unroll
      for(int ni = 0; ni < 4; ++ni){
        int row = wc*64 + ni*16 + (lane & 15);
        bf[ni] = *(const short8*)&sB[row][(((ka >> 3) ^ (row & 7)) * 8)];
      }
      #pragma unroll
      for(int mi = 0; mi < 4; ++mi)
        #pragma unroll
        for(int ni = 0; ni < 4; ++ni)
          acc[mi][ni] = __builtin_amdgcn_mfma_f32_16x16x32_bf16(af[mi], bf[ni], acc[mi][ni], 0, 0, 0);
    }
    __syncthreads();
  }
  unsigned short* op = Out + (size_t)buf * bufStride + (size_t)bl * CCH * HW;
  #pragma unroll
  for(int mi = 0; mi < 4; ++mi){
    int oq = (o0 + wr*64 + mi*16) / 4 + (lane >> 4);
    #pragma unroll
    for(int ni = 0; ni < 4; ++ni){
      int p = p0 + wc*64 + ni*16 + (lane & 15);
      uint2 pk;
      pk.x = (unsigned)f2bf(acc[mi][ni][0]) | ((unsigned)f2bf(acc[mi][ni][1]) << 16);
      pk.y = (unsigned)f2bf(acc[mi][ni][2]) | ((unsigned)f2bf(acc[mi][ni][3]) << 16);
      *(uint2*)(op + ((size_t)oq * HW + p) * 4) = pk;
    }
  }
}

// ---- K6: fused out-GEMM + final LN. Tile 512(ch) x 64(px), 256 thr, 2 blocks/CU. ----
__global__ __launch_bounds__(256, 2)
void outln_kernel(const unsigned short* __restrict__ W, const unsigned short* __restrict__ att,
                  const float* __restrict__ g, float* __restrict__ outp){
  __shared__ unsigned short sA[512][64], sB[64][64];
  __shared__ float ps[4][64], pss[4][64];
  __shared__ float gsh[512];
  int bl = blockIdx.y;
  int p0 = blockIdx.x * 64;
  const unsigned short* bsrc = att + (size_t)bl * HW * CCH;
  int t = threadIdx.x, lane = t & 63, wid = t >> 6;
  int kl = lane & 15, kh = lane >> 4;
  int srow  = lane >> 3;
  int scol8 = ((lane & 7) ^ srow) * 8;
  gsh[t] = g[t]; gsh[t + 256] = g[t + 256];
  f4 acc[8][4] = {};
  for(int kt = 0; kt < 8; ++kt){
    int k0 = kt * 64;
    #pragma unroll
    for(int i = 0; i < 16; ++i){
      int r = wid * 128 + i * 8;
      const unsigned short* gA = W + (size_t)(r + srow) * CCH + k0 + scol8;
      __builtin_amdgcn_global_load_lds(
          (const __attribute__((address_space(1))) void*)gA,
          (__attribute__((address_space(3))) void*)&sA[r][0], 16, 0, 0);
    }
    #pragma unroll
    for(int i = 0; i < 2; ++i){
      int r = wid * 16 + i * 8;
      const unsigned short* gB = bsrc + (size_t)(p0 + r + srow) * CCH + k0 + scol8;
      __builtin_amdgcn_global_load_lds(
          (const __attribute__((address_space(1))) void*)gB,
          (__attribute__((address_space(3))) void*)&sB[r][0], 16, 0, 0);
    }
    __syncthreads();
    #pragma unroll
    for(int kk = 0; kk < 64; kk += 32){
      int ka = kk + kh * 8;
      short8 af[8], bf[4];
      #pragma unroll
      for(int mi = 0; mi < 8; ++mi){
        int row = wid*128 + mi*16 + kl;
        af[mi] = *(const short8*)&sA[row][(((ka >> 3) ^ (row & 7)) * 8)];
      }
      #pragma unroll
      for(int ni = 0; ni < 4; ++ni){
        int row = ni*16 + kl;
        bf[ni] = *(const short8*)&sB[row][(((ka >> 3) ^ (row & 7)) * 8)];
      }
      #pragma unroll
      for(int mi = 0; mi < 8; ++mi)
        #pragma unroll
        for(int ni = 0; ni < 4; ++ni)
          acc[mi][ni] = __builtin_amdgcn_mfma_f32_16x16x32_f16(
              __builtin_bit_cast(half8, af[mi]), __builtin_bit_cast(half8, bf[ni]),
              acc[mi][ni], 0, 0, 0);
    }
    __syncthreads();
  }
  float s[4], ss[4];
  #pragma unroll
  for(int ni = 0; ni < 4; ++ni){
    float a = 0.f, b = 0.f;
    #pragma unroll
    for(int mi = 0; mi < 8; ++mi)
      #pragma unroll
      for(int j = 0; j < 4; ++j){
        float v = acc[mi][ni][j];
        a += v; b += v * v;
      }
    a += __shfl_xor(a, 16); a += __shfl_xor(a, 32);
    b += __shfl_xor(b, 16); b += __shfl_xor(b, 32);
    s[ni] = a; ss[ni] = b;
  }
  if(kh == 0){
    #pragma unroll
    for(int ni = 0; ni < 4; ++ni){
      int p = ni*16 + kl;
      ps[wid][p] = s[ni]; pss[wid][p] = ss[ni];
    }
  }
  __syncthreads();
  float mean[4], rstd[4];
  #pragma unroll
  for(int ni = 0; ni < 4; ++ni){
    int p = ni*16 + kl;
    float tot  = ps[0][p] + ps[1][p] + ps[2][p] + ps[3][p];
    float tots = pss[0][p] + pss[1][p] + pss[2][p] + pss[3][p];
    float m = tot * (1.0f/512.0f);
    mean[ni] = m;
    rstd[ni] = rsqrtf(tots * (1.0f/512.0f) - m*m + 1e-5f);
  }
  float* op = outp + (size_t)bl * CCH * HW;
  #pragma unroll
  for(int mi = 0; mi < 8; ++mi){
    int o = wid*128 + mi*16 + kh * 4;
    #pragma unroll
    for(int ni = 0; ni < 4; ++ni){
      int p = p0 + ni*16 + kl;
      #pragma unroll
      for(int j = 0; j < 4; ++j)
        op[(size_t)(o + j) * HW + p] = (acc[mi][ni][j] - mean[ni]) * rstd[ni] * gsh[o + j];
    }
  }
}

// ---- K7: dw3x3(K,V) fused + ctx partial via MFMA (fp16 in, f32 acc). 8 p-slices.
// Partials accumulated straight into ctxf/ksf via f32 atomicAdd (accumulators are
// zero-filled by ln_tr_fused); no separate reduce kernel. ----
__global__ __launch_bounds__(256)
void ctx_kernel(const unsigned short* __restrict__ Kq, const unsigned short* __restrict__ Vq,
                float* __restrict__ ctxf, float* __restrict__ ksf,
                const float* __restrict__ k_dw, const float* __restrict__ v_dw){
  __shared__ unsigned short ek[2][64][64];   // exp(k') f16, [d][p] XOR-swizzled
  __shared__ unsigned short vv[2][64][64];   // v' f16,     [e][p] XOR-swizzled
  __shared__ float wtk[9][68], wtv[9][68];
  __shared__ float ksred[16][68];
  int bh = blockIdx.x, sl = blockIdx.y;
  int bl = bh >> 3, h = bh & 7;
  int t = threadIdx.x, lane = t & 63, wid = t >> 6;
  int wr = wid >> 1, wc = wid & 1;
  int dq = t >> 4, j = t & 15, x4 = j * 4;
  int d0 = dq * 4;
  int kl = lane & 15, kh = lane >> 4;
  const unsigned short* kq = Kq + ((size_t)(bl*128 + h*16 + dq)) * HW * 4;
  const unsigned short* vq = Vq + ((size_t)(bl*128 + h*16 + dq)) * HW * 4;
  for(int i = t; i < 576; i += 256){
    int d = i / 9, tp = i % 9;
    wtk[tp][d] = k_dw[(size_t)(h*64 + d)*9 + tp];
    wtv[tp][d] = v_dw[(size_t)(h*64 + d)*9 + tp];
  }
  __syncthreads();
  f4 acc[2][2] = {};
  f4 ksacc = {0,0,0,0};
  const f4 zf = {0,0,0,0};
  for(int it = 0; it < 8; ++it){
    int cb = it & 1;
    int row = sl * 8 + it;
    f4 ok_[4] = {zf, zf, zf, zf}, ov_[4] = {zf, zf, zf, zf};
    #pragma unroll
    for(int dy = 0; dy < 3; ++dy){
      int r = row + dy - 1;
      if(r >= 0 && r < 64){
        f4 in[6];
        #pragma unroll
        for(int px = 0; px < 6; ++px){
          int x = x4 - 1 + px;
          in[px] = (x >= 0 && x < 64) ? ld_bf4(kq + ((size_t)r*64 + x)*4) : zf;
        }
        #pragma unroll
        for(int dx = 0; dx < 3; ++dx){
          f4 w = *(const f4*)&wtk[dy*3+dx][d0];
          #pragma unroll
          for(int xo = 0; xo < 4; ++xo) ok_[xo] += w * in[xo + dx];
        }
        #pragma unroll
        for(int px = 0; px < 6; ++px){
          int x = x4 - 1 + px;
          in[px] = (x >= 0 && x < 64) ? ld_bf4(vq + ((size_t)r*64 + x)*4) : zf;
        }
        #pragma unroll
        for(int dx = 0; dx < 3; ++dx){
          f4 w = *(const f4*)&wtv[dy*3+dx][d0];
          #pragma unroll
          for(int xo = 0; xo < 4; ++xo) ov_[xo] += w * in[xo + dx];
        }
      }
    }
    #pragma unroll
    for(int dd = 0; dd < 4; ++dd){
      int d = d0 + dd;
      int col = (((j >> 1) ^ (d & 7)) << 3) | ((j & 1) << 2);
      ushort4 pe, pv;
      unsigned short eh[4];
      #pragma unroll
      for(int xo = 0; xo < 4; ++xo){
        float ev = __expf(ok_[xo][dd]);
        _Float16 hv = (_Float16)ev;
        ksacc[dd] += (float)hv;          // ks from identically-rounded exp values
        eh[xo] = __builtin_bit_cast(unsigned short, hv);
      }
      pe.x = eh[0]; pe.y = eh[1]; pe.z = eh[2]; pe.w = eh[3];
      pv.x = f2h(ov_[0][dd]); pv.y = f2h(ov_[1][dd]);
      pv.z = f2h(ov_[2][dd]); pv.w = f2h(ov_[3][dd]);
      *(ushort4*)&ek[cb][d][col] = pe;
      *(ushort4*)&vv[cb][d][col] = pv;
    }
    __syncthreads();
    #pragma unroll
    for(int kk = 0; kk < 64; kk += 32){
      int g = (kk >> 3) + kh;
      short8 af[2], bfr[2];
      #pragma unroll
      for(int mi = 0; mi < 2; ++mi){
        int rowa = wr*32 + mi*16 + kl;
        af[mi] = *(const short8*)&ek[cb][rowa][((g ^ (rowa & 7)) << 3)];
      }
      #pragma unroll
      for(int ni = 0; ni < 2; ++ni){
        int rowb = wc*32 + ni*16 + kl;
        bfr[ni] = *(const short8*)&vv[cb][rowb][((g ^ (rowb & 7)) << 3)];
      }
      #pragma unroll
      for(int mi = 0; mi < 2; ++mi)
        #pragma unroll
        for(int ni = 0; ni < 2; ++ni)
          acc[mi][ni] = __builtin_amdgcn_mfma_f32_16x16x32_f16(
              __builtin_bit_cast(half8, af[mi]), __builtin_bit_cast(half8, bfr[ni]),
              acc[mi][ni], 0, 0, 0);
    }
  }
  // C/D layout: col=lane&15 -> e, row=(lane>>4)*4+jj -> d within tile
  float* cp = ctxf + (size_t)bh * 4096;
  #pragma unroll
  for(int mi = 0; mi < 2; ++mi){
    int dbase = wr*32 + mi*16 + kh*4;
    #pragma unroll
    for(int ni = 0; ni < 2; ++ni){
      int e = wc*32 + ni*16 + kl;
      #pragma unroll
      for(int jj = 0; jj < 4; ++jj)
        atomicAdd(&cp[(size_t)(dbase + jj) * 64 + e], acc[mi][ni][jj]);
    }
  }
  __syncthreads();
  *(f4*)&ksred[j][d0] = ksacc;
  __syncthreads();
  if(t < 64){
    float s = 0.f;
    #pragma unroll
    for(int jj = 0; jj < 16; ++jj) s += ksred[jj][t];
    atomicAdd(&ksf[(size_t)bh * 64 + t], s);
  }
}

// ---- K8: dw3x3(Q) + softmax_d + MFMA out = q_sm·(ctx/ks) + silu -> fp16 att[p][c] ----
__global__ __launch_bounds__(256)
void att2_kernel(const unsigned short* __restrict__ Qq, const float* __restrict__ ctxf,
                 const float* __restrict__ ksf, const float* __restrict__ q_dw,
                 unsigned short* __restrict__ att){
  __shared__ float qs[64][132];               // conv-Q output, [d][p] f32
  __shared__ unsigned short qb[128][68];      // softmaxed q, [p][d] bf16 (B-operand)
  __shared__ unsigned short ctxb[64][68];     // ctx, [e][d] bf16 (A-operand)
  __shared__ float kinv[64];
  int bidx = blockIdx.x;
  int chunk = (bidx & 31) * 128;
  int bh = bidx >> 5;
  int bl = bh >> 3, h = bh & 7;
  int t = threadIdx.x, lane = t & 63, wid = t >> 6;
  if(t < 64) kinv[t] = 1.0f / ksf[(size_t)bh * 64 + t];
  __syncthreads();
  // ctx load (global [d][e] f32 unnormalized sums -> LDS [e][d] bf16, x 1/ks[d])
  const float* cb = ctxf + (size_t)bh * 4096;
  for(int i = t; i < 4096; i += 256)
    ctxb[i & 63][i >> 6] = f2bf(cb[i] * kinv[i >> 6]);
  // conv-Q from quad layout
  {
    int dq = t >> 4, j = t & 15;
    int d0 = dq * 4;
    int row = (chunk >> 6) + (j >> 3), x8 = (j & 7) * 8;
    const unsigned short* qbp = Qq + ((size_t)(bl*128 + h*16 + dq)) * HW * 4;
    f4 wq[9];
    #pragma unroll
    for(int tp = 0; tp < 9; ++tp)
      #pragma unroll
      for(int dd = 0; dd < 4; ++dd)
        wq[tp][dd] = q_dw[(size_t)(h*64 + d0 + dd)*9 + tp];
    const f4 zf = {0,0,0,0};
    f4 out[8] = {zf, zf, zf, zf, zf, zf, zf, zf};
    #pragma unroll
    for(int dy = 0; dy < 3; ++dy){
      int r = row + dy - 1;
      if(r >= 0 && r < 64){
        f4 in[10];
        #pragma unroll
        for(int px = 0; px < 10; ++px){
          int x = x8 - 1 + px;
          f4 v = zf;
          if(x >= 0 && x < 64) v = ld_bf4(qbp + ((size_t)r*64 + x)*4);
          in[px] = v;
        }
        #pragma unroll
        for(int dx = 0; dx < 3; ++dx){
          f4 w = wq[dy*3+dx];
          #pragma unroll
          for(int xo = 0; xo < 8; ++xo)
            out[xo] += w * in[xo + dx];
        }
      }
    }
    #pragma unroll
    for(int xo = 0; xo < 8; ++xo)
      #pragma unroll
      for(int dd = 0; dd < 4; ++dd)
        qs[d0 + dd][j*8 + xo] = out[xo][dd];
  }
  __syncthreads();
  // softmax over d per pixel + bf16 convert -> qb[p][d]
  {
    int p = t >> 1, half = t & 1;
    float mx = -1e30f;
    #pragma unroll
    for(int jj = 0; jj < 32; ++jj) mx = fmaxf(mx, qs[half*32 + jj][p]);
    mx = fmaxf(mx, __shfl_xor(mx, 1));
    float s = 0.f;
    #pragma unroll
    for(int jj = 0; jj < 32; ++jj) s += __expf(qs[half*32 + jj][p] - mx);
    s += __shfl_xor(s, 1);
    float inv = 0.125f / s;
    #pragma unroll
    for(int jj = 0; jj < 16; ++jj){
      int d = half*32 + jj*2;
      float v0 = __expf(qs[d][p]     - mx) * inv;
      float v1 = __expf(qs[d + 1][p] - mx) * inv;
      unsigned pk = (unsigned)f2bf(v0) | ((unsigned)f2bf(v1) << 16);
      *(unsigned*)&qb[p][d] = pk;
    }
  }
  __syncthreads();
  // MFMA: out[e][p] = sum_d ctx[e][d]*q[p][d]; wave w owns p rows w*32..w*32+31
  f4 acc[4][2] = {};
  #pragma unroll
  for(int et = 0; et < 4; ++et){
    short8 a0 = *(const short8*)&ctxb[et*16 + (lane & 15)][(lane >> 4) * 8];
    short8 a1 = *(const short8*)&ctxb[et*16 + (lane & 15)][32 + (lane >> 4) * 8];
    #pragma unroll
    for(int pt = 0; pt < 2; ++pt){
      int prow = wid*32 + pt*16 + (lane & 15);
      short8 b0 = *(const short8*)&qb[prow][(lane >> 4) * 8];
      short8 b1 = *(const short8*)&qb[prow][32 + (lane >> 4) * 8];
      acc[et][pt] = __builtin_amdgcn_mfma_f32_16x16x32_bf16(a0, b0, acc[et][pt], 0, 0, 0);
      acc[et][pt] = __builtin_amdgcn_mfma_f32_16x16x32_bf16(a1, b1, acc[et][pt], 0, 0, 0);
    }
  }
  // silu + fp16 pack + store (C/D: col=lane&15 -> p, row=(lane>>4)*4+j -> e)
  #pragma unroll
  for(int et = 0; et < 4; ++et){
    int e0 = et*16 + (lane >> 4) * 4;
    #pragma unroll
    for(int pt = 0; pt < 2; ++pt){
      int p = chunk + wid*32 + pt*16 + (lane & 15);
      unsigned short hv[4];
      #pragma unroll
      for(int j = 0; j < 4; ++j){
        float x = acc[et][pt][j];
        hv[j] = f2h(x / (1.f + __expf(-x)));
      }
      uint2 pk;
      pk.x = (unsigned)hv[0] | ((unsigned)hv[1] << 16);
      pk.y = (unsigned)hv[2] | ((unsigned)hv[3] << 16);
      *(uint2*)(att + ((size_t)bl * HW + p) * CCH + h*64 + e0) = pk;
    }
  }
}

extern "C" void kernel_launch(void* const* d_in, const int* in_sizes, int n_in,
                              void* d_out, int out_size, void* d_ws, size_t ws_size,
                              hipStream_t stream){
  const float* fmap   = (const float*)d_in[0];
  const float* g_norm = (const float*)d_in[1];
  const float* q_w1   = (const float*)d_in[2];
  const float* q_dw   = (const float*)d_in[3];
  const float* k_w1   = (const float*)d_in[4];
  const float* k_dw   = (const float*)d_in[5];
  const float* v_w1   = (const float*)d_in[6];
  const float* v_dw   = (const float*)d_in[7];
  const float* out_w  = (const float*)d_in[8];
  const float* g_out  = (const float*)d_in[9];
  float* outp = (float*)d_out;

  const size_t WQKV = 1536*512*2;
  const size_t WOUT = 512*512*2;
  const size_t PERB = 19038208ull;
  int G = 16;
  while(G > 1 && (WQKV + WOUT + (size_t)G*PERB) > ws_size) G >>= 1;
  if((WQKV + WOUT + (size_t)G*PERB) > ws_size) return;

  char* w = (char*)d_ws;
  unsigned short* wqkv = (unsigned short*)w;
  unsigned short* wout = (unsigned short*)(w + WQKV);
  char* gb = w + WQKV + WOUT;
  unsigned short* xt  = (unsigned short*)gb;
  unsigned short* Qb  = (unsigned short*)(gb + (size_t)G *  4194304);
  float* ksf  = (float*)(gb + (size_t)G * 18874368);
  float* ctxf = (float*)(gb + (size_t)G * 18907136);
  unsigned short* Kb = Qb + (size_t)G * CCH * HW;
  unsigned short* Vb = Kb + (size_t)G * CCH * HW;
  // zero-span for atomic accumulators: from ksf through end of ctxf (contiguous tail of PERB)
  float* zbase = ksf;
  int zn = G * 40960;   // G*(19038208-18874368)/4 floats

  wsplit_all_kernel<<<4096, 256, 0, stream>>>(q_w1, k_w1, v_w1, out_w, wqkv, wout);

  for(int b0 = 0; b0 < 16; b0 += G){
    const float* fg = fmap + (size_t)b0 * CCH * HW;
    float* og = outp + (size_t)b0 * CCH * HW;
    ln_tr_fused<<<G*128, 256, 0, stream>>>(fg, g_norm, xt, zbase, zn);
    gemm_bt_kernel<<<dim3(32,12,G), 256, 0, stream>>>(wqkv, xt, Qb, (size_t)G * CCH * HW);
    ctx_kernel<<<dim3(G*8,8), 256, 0, stream>>>(Kb, Vb, ctxf, ksf, k_dw, v_dw);
    att2_kernel<<<G*256, 256, 0, stream>>>(Qb, ctxf, ksf, q_dw, xt);
    outln_kernel<<<dim3(64, G), 256, 0, stream>>>(wout, xt, g_out, og);
  }
}